// Round 14
// baseline (693.364 us; speedup 1.0000x reference)
//
#include <hip/hip_runtime.h>
#include <hip/hip_bf16.h>

// Problem constants (fixed by reference setup_inputs)
#define M_TOK 16384   // B*S = 8*2048
#define DK    4096    // D_IN
#define DN    4096    // D_OUT
#define NE    8       // experts
#define NR    16      // lora rank
#define ERC   128     // E*R
#define RAC   160     // padded router+A columns (8 + 128 + 24 pad)
#define NT64  66      // K-tiles of 64: 64 base + 2 expert

typedef __attribute__((ext_vector_type(8))) short bfrag;    // 8 bf16 (4 VGPRs)
typedef __attribute__((ext_vector_type(4))) float f32x4;    // 16x16 MFMA acc
typedef __attribute__((ext_vector_type(16))) float f32x16;  // 32x32 MFMA acc

__device__ __forceinline__ unsigned short f2bf(float f) {
  unsigned u = __builtin_bit_cast(unsigned, f);
  unsigned rounding = 0x7FFFu + ((u >> 16) & 1u);
  u += rounding;
  return (unsigned short)(u >> 16);
}

__device__ __forceinline__ void load_lds16(const void* g, void* l) {
  __builtin_amdgcn_global_load_lds(
      (__attribute__((address_space(1))) void*)(g),
      (__attribute__((address_space(3))) void*)(l), 16, 0, 0);
}

// ---------- conversion kernels ----------
__global__ void k_cvt(const float* __restrict__ in, unsigned short* __restrict__ out, long n4) {
  long i = (long)blockIdx.x * blockDim.x + threadIdx.x;
  long stride = (long)gridDim.x * blockDim.x;
  for (; i < n4; i += stride) {
    float4 v = reinterpret_cast<const float4*>(in)[i];
    ushort4 o;
    o.x = f2bf(v.x); o.y = f2bf(v.y); o.z = f2bf(v.z); o.w = f2bf(v.w);
    reinterpret_cast<ushort4*>(out)[i] = o;
  }
}

// RA[c][k], c in [0,160): c<8 -> W_router[c][k]; 8<=c<136 -> lora_A[e][k][r]; pad 0
__global__ void k_build_ra(const float* __restrict__ Wr, const float* __restrict__ lA,
                           unsigned short* __restrict__ RA) {
  int idx = blockIdx.x * 256 + threadIdx.x;
  if (idx >= RAC * DK) return;
  int c = idx >> 12;          // /4096
  int k = idx & (DK - 1);
  float v = 0.f;
  if (c < NE) {
    v = Wr[c * DK + k];
  } else if (c < NE + ERC) {
    int er = c - NE;
    int e = er >> 4, r = er & 15;
    v = lA[((long)e * DK + k) * NR + r];
  }
  RA[idx] = f2bf(v);
}

// BT[n][kp] = lora_B[kp/16][kp%16][n]  -> [DN][128] bf16
__global__ void k_build_bt(const float* __restrict__ lB, unsigned short* __restrict__ BT) {
  int idx = blockIdx.x * 256 + threadIdx.x;
  if (idx >= DN * ERC) return;
  int n = idx >> 7;
  int kp = idx & 127;
  BT[idx] = f2bf(lB[(long)kp * DN + n]);
}

// ---------- fused small kernel (R9 proven) -----------------------------------
__global__ __launch_bounds__(256, 2)
void k_small_fused(const float* __restrict__ x, const unsigned short* __restrict__ RA,
                   unsigned short* __restrict__ Xb, const float* __restrict__ b_router,
                   unsigned short* __restrict__ Gout) {
  __shared__ unsigned short At[64 * 64];
  __shared__ unsigned short Bt[RAC * 64];
  __shared__ float Hl[64][160];
  __shared__ float Wl[64][NE];
  int m0 = blockIdx.x * 64;
  int tid = threadIdx.x;
  int lane = tid & 63, wid = tid >> 6;
  int wr = wid >> 1, wc = wid & 1;      // 2x2 waves; wave tile 32 x 80
  int l16 = lane & 15, lhi = lane >> 4;
  f32x4 acc[2][5] = {};
  int row = tid >> 2, c16 = (tid & 3) * 16;
  int byteoff = tid * 16;
  for (int k0 = 0; k0 < DK; k0 += 64) {
    const float* xs = x + (long)(m0 + row) * DK + k0 + c16;
    float4 v0 = *(const float4*)(xs);
    float4 v1 = *(const float4*)(xs + 4);
    float4 v2 = *(const float4*)(xs + 8);
    float4 v3 = *(const float4*)(xs + 12);
    bfrag lo, hi;
    lo[0] = (short)f2bf(v0.x); lo[1] = (short)f2bf(v0.y);
    lo[2] = (short)f2bf(v0.z); lo[3] = (short)f2bf(v0.w);
    lo[4] = (short)f2bf(v1.x); lo[5] = (short)f2bf(v1.y);
    lo[6] = (short)f2bf(v1.z); lo[7] = (short)f2bf(v1.w);
    hi[0] = (short)f2bf(v2.x); hi[1] = (short)f2bf(v2.y);
    hi[2] = (short)f2bf(v2.z); hi[3] = (short)f2bf(v2.w);
    hi[4] = (short)f2bf(v3.x); hi[5] = (short)f2bf(v3.y);
    hi[6] = (short)f2bf(v3.z); hi[7] = (short)f2bf(v3.w);
    unsigned short* xb = Xb + (long)(m0 + row) * DK + k0 + c16;
    *(bfrag*)xb = lo;
    *(bfrag*)(xb + 8) = hi;
    *(bfrag*)&At[row * 64 + c16] = lo;
    *(bfrag*)&At[row * 64 + c16 + 8] = hi;
#pragma unroll
    for (int r = 0; r < 5; r++) {
      int off = r * 4096 + byteoff;
      int rrow = off >> 7, colb = off & 127;
      load_lds16((const char*)RA + ((long)rrow * DK + k0) * 2 + colb, (char*)Bt + off);
    }
    __syncthreads();
#pragma unroll
    for (int kk = 0; kk < 2; kk++) {
      bfrag a[2], b[5];
#pragma unroll
      for (int m = 0; m < 2; m++)
        a[m] = *(const bfrag*)&At[(wr * 32 + m * 16 + l16) * 64 + kk * 32 + lhi * 8];
#pragma unroll
      for (int n = 0; n < 5; n++)
        b[n] = *(const bfrag*)&Bt[(wc * 80 + n * 16 + l16) * 64 + kk * 32 + lhi * 8];
#pragma unroll
      for (int m = 0; m < 2; m++)
#pragma unroll
        for (int n = 0; n < 5; n++)
          acc[m][n] = __builtin_amdgcn_mfma_f32_16x16x32_bf16(a[m], b[n], acc[m][n], 0, 0, 0);
    }
    __syncthreads();
  }
#pragma unroll
  for (int m = 0; m < 2; m++)
#pragma unroll
    for (int n = 0; n < 5; n++) {
      int col = wc * 80 + n * 16 + l16;
      int trow = wr * 32 + m * 16 + lhi * 4;
#pragma unroll
      for (int j = 0; j < 4; j++)
        Hl[trow + j][col] = acc[m][n][j];
    }
  __syncthreads();
  if (tid < 64) {
    float z[NE], zs[NE];
#pragma unroll
    for (int e = 0; e < NE; e++) { z[e] = Hl[tid][e] + b_router[e]; zs[e] = z[e]; }
#pragma unroll
    for (int i = 1; i < NE; i++) {
      float key = zs[i];
      int j = i - 1;
      while (j >= 0 && zs[j] < key) { zs[j + 1] = zs[j]; j--; }
      zs[j + 1] = key;
    }
    float cums[NE];
    float cum = 0.f;
#pragma unroll
    for (int j = 0; j < NE; j++) { cum += zs[j]; cums[j] = cum; }
    int kz = 0;
#pragma unroll
    for (int j = 0; j < NE; j++)
      if (1.f + (float)(j + 1) * zs[j] > cums[j]) kz = j + 1;
    float tau = (cums[kz - 1] - 1.f) / (float)kz;
#pragma unroll
    for (int e = 0; e < NE; e++)
      Wl[tid][e] = fmaxf(z[e] - tau, 0.f);
  }
  __syncthreads();
  for (int idx = tid; idx < 64 * ERC; idx += 256) {
    int tk = idx >> 7, er = idx & 127;
    Gout[(long)(m0 + tk) * ERC + er] = f2bf(Wl[tk][er >> 4] * Hl[tk][NE + er]);
  }
}

// ---------- main GEMM: 2-phase 256x256, BK=64, 32x32x16 MFMA -----------------
// out = Xb @ Wb^T + bias + G @ BT^T as 66 K-tiles of 64 (64 base + 2 expert).
// Identical to the R11-proven kernel (same LDS geometry [2dbuf][2half][128][64],
// same staging, same swizzle, same sync ledger) EXCEPT the MFMA shape:
// mfma_f32_32x32x16_bf16 (ubench 2495 TF, 99.8% of dense peak) replaces
// 16x16x32 (2075 TF). Same FLOP, same LDS bytes, but the MFMA pipe floor per
// K-tile drops 2486 -> 2066 cyc and instruction count halves.
// Fragment layouts (by strict analogy with the correctness-proven 16x16x32
// usage; C/D is m74/m101-verified):
//   A: lane holds A[lane&31][(lane>>5)*8 + j] -> read 8 contiguous k at row
//      base + (lane&31); same row-major [row][64] LDS rows as before.
//   B: lane holds B[k][lane&31], k contiguous -> our W-row-major reads give
//      exactly this (col = lane&31 = W row index n).
//   C/D: col = lane&31, row = (reg&3) + 8*(reg>>2) + 4*(lane>>5).
// Bank check (store swizzle unchanged: LDS(row,slot) = global(row, slot^(row&7));
// read phys = (ks*2 + (lane>>5)) ^ (lane&7)): each b128 hits every bank
// exactly 8x = the 1024B/128B floor -> 0 conflicts.
struct KtArgs {
  const unsigned short *pX, *pW, *pG, *pT;
  int aB, bB, tid8;
  int swk[4];           // per-kstep swizzled granule offset (shorts)
};

__device__ __forceinline__ void stage_half(unsigned short* lds, const KtArgs& A,
                                           int u, int arr, int h) {
  unsigned short* dst = lds + arr * 32768 + (u & 1) * 16384 + h * 8192 + A.tid8;
  if (u < 64) {
    const unsigned short* s = (arr ? A.pW : A.pX) + (long)(h * 128) * DK + (long)u * 64;
    load_lds16(s, dst);
    load_lds16(s + (long)64 * DK, dst + 4096);
  } else {
    const unsigned short* s = (arr ? A.pT : A.pG) + (long)(h * 128) * ERC + (long)(u - 64) * 64;
    load_lds16(s, dst);
    load_lds16(s + (long)64 * ERC, dst + 4096);
  }
}

template<bool AST, bool BST, int VMB>
__device__ __forceinline__ void ktile(int t, unsigned short* lds, const KtArgs& A,
                                      f32x16 (&acc)[4][2]) {
  unsigned short* L = lds + (t & 1) * 16384;
  bfrag b[2][4], a[2][4], a2[2][4];
  // ---- phA: read B both n-tiles (8 b128) + A mt0,1 (8); stage A(t+1) ----
#pragma unroll
  for (int nt = 0; nt < 2; nt++)
#pragma unroll
    for (int ks = 0; ks < 4; ks++)
      b[nt][ks] = *(const bfrag*)&L[A.bB + nt * 2048 + A.swk[ks]];
#pragma unroll
  for (int mt = 0; mt < 2; mt++)
#pragma unroll
    for (int ks = 0; ks < 4; ks++)
      a[mt][ks] = *(const bfrag*)&L[A.aB + mt * 2048 + A.swk[ks]];
  if constexpr (AST) {
    stage_half(lds, A, t + 1, 0, 0);
    stage_half(lds, A, t + 1, 0, 1);
  }
  asm volatile("s_waitcnt lgkmcnt(8)" ::: "memory");
  __builtin_amdgcn_s_barrier();
  asm volatile("s_waitcnt lgkmcnt(0)" ::: "memory");
  __builtin_amdgcn_sched_barrier(0);
  __builtin_amdgcn_s_setprio(1);
#pragma unroll
  for (int mt = 0; mt < 2; mt++)
#pragma unroll
    for (int nt = 0; nt < 2; nt++)
#pragma unroll
      for (int ks = 0; ks < 4; ks++)
        acc[mt][nt] = __builtin_amdgcn_mfma_f32_32x32x16_bf16(a[mt][ks], b[nt][ks], acc[mt][nt], 0, 0, 0);
  __builtin_amdgcn_s_setprio(0);
  __builtin_amdgcn_s_barrier();
  // ---- phB: read A mt2,3 (8); stage B(t+2) both halves ----
#pragma unroll
  for (int mt = 0; mt < 2; mt++)
#pragma unroll
    for (int ks = 0; ks < 4; ks++)
      a2[mt][ks] = *(const bfrag*)&L[A.aB + (2 + mt) * 2048 + A.swk[ks]];
  if constexpr (BST) {
    stage_half(lds, A, t + 2, 1, 0);
    stage_half(lds, A, t + 2, 1, 1);
  }
  __builtin_amdgcn_s_barrier();
  asm volatile("s_waitcnt lgkmcnt(0)" ::: "memory");
  __builtin_amdgcn_sched_barrier(0);
  __builtin_amdgcn_s_setprio(1);
#pragma unroll
  for (int mt = 0; mt < 2; mt++)
#pragma unroll
    for (int nt = 0; nt < 2; nt++)
#pragma unroll
      for (int ks = 0; ks < 4; ks++)
        acc[2 + mt][nt] = __builtin_amdgcn_mfma_f32_32x32x16_bf16(a2[mt][ks], b[nt][ks], acc[2 + mt][nt], 0, 0, 0);
  __builtin_amdgcn_s_setprio(0);
  if constexpr (VMB == 4)      asm volatile("s_waitcnt vmcnt(4)\n\ts_barrier" ::: "memory");
  else if constexpr (VMB == 0) asm volatile("s_waitcnt vmcnt(0)\n\ts_barrier" ::: "memory");
  // VMB < 0: last tile, no boundary
}

__global__ __launch_bounds__(512, 2)
void k_gemm_main(const unsigned short* __restrict__ X, const unsigned short* __restrict__ W,
                 const unsigned short* __restrict__ G, const unsigned short* __restrict__ BT,
                 const float* __restrict__ bias, float* __restrict__ out) {
  // A: [2 dbuf][2 half][128][64] at 0; B: same at 32768 (shorts). 128 KiB total.
  __shared__ unsigned short lds[65536];
  int bid = blockIdx.x;
  // XCD-aware swizzle: 1024 workgroups, 8 XCDs -> contiguous chunks of 128
  int swz = (bid & 7) * 128 + (bid >> 3);
  int bm = swz >> 4, bn = swz & 15;
  int m0 = bm * 256, n0 = bn * 256;
  int tid = threadIdx.x;
  int lane = tid & 63, wid = tid >> 6;
  int wr = wid >> 2, wc = wid & 3;      // 2x4 waves; wave tile 128 x 64
  int l31 = lane & 31, lhi5 = lane >> 5, l7 = lane & 7;

  KtArgs A;
#pragma unroll
  for (int ks = 0; ks < 4; ks++)
    A.swk[ks] = ((ks * 2 + lhi5) ^ l7) * 8;
  A.aB = wr * 8192 + l31 * 64;                          // + mt*2048
  A.bB = 32768 + (wc >> 1) * 8192 + ((wc & 1) * 64 + l31) * 64;  // + nt*2048
  A.tid8 = tid * 8;
  int swz8 = ((tid & 7) ^ ((tid >> 3) & 7)) * 8;        // pre-swizzled source slot
  int r0 = tid >> 3;
  A.pX = X + (long)(m0 + r0) * DK + swz8;
  A.pW = W + (long)(n0 + r0) * DK + swz8;
  A.pG = G + (long)(m0 + r0) * ERC + swz8;
  A.pT = BT + (long)(n0 + r0) * ERC + swz8;

  f32x16 acc[4][2] = {};

  // prologue: A(0) both halves, B(0) both halves, B(1) both halves (12 loads).
  // vmcnt(4) keeps B(1) x4 in flight; A(0), B(0) drained -> tile 0 certified.
  stage_half(lds, A, 0, 0, 0);
  stage_half(lds, A, 0, 0, 1);
  stage_half(lds, A, 0, 1, 0);
  stage_half(lds, A, 0, 1, 1);
  stage_half(lds, A, 1, 1, 0);
  stage_half(lds, A, 1, 1, 1);
  asm volatile("s_waitcnt vmcnt(4)\n\ts_barrier" ::: "memory");

  for (int t = 0; t < 64; t++)
    ktile<true, true, 4>(t, lds, A, acc);
  ktile<true, false, 0>(64, lds, A, acc);
  ktile<false, false, -1>(65, lds, A, acc);

  // epilogue: bias + f32 store (32x32 C/D: col=lane&31,
  // row = (reg&3) + 8*(reg>>2) + 4*(lane>>5))
#pragma unroll
  for (int mt = 0; mt < 4; mt++)
#pragma unroll
    for (int nt = 0; nt < 2; nt++) {
      int col = n0 + wc * 64 + nt * 32 + l31;
      float bv = bias[col];
#pragma unroll
      for (int r = 0; r < 16; r++) {
        int row = m0 + wr * 128 + mt * 32 + (r & 3) + 8 * (r >> 2) + 4 * lhi5;
        out[(long)row * DN + col] = acc[mt][nt][r] + bv;
      }
    }
}

extern "C" void kernel_launch(void* const* d_in, const int* in_sizes, int n_in,
                              void* d_out, int out_size, void* d_ws, size_t ws_size,
                              hipStream_t stream) {
  const float* x        = (const float*)d_in[0];
  const float* W_base   = (const float*)d_in[1];
  const float* b_base   = (const float*)d_in[2];
  const float* W_router = (const float*)d_in[3];
  const float* b_router = (const float*)d_in[4];
  const float* lora_A   = (const float*)d_in[5];
  const float* lora_B   = (const float*)d_in[6];
  float* out = (float*)d_out;

  char* ws = (char*)d_ws;
  unsigned short* Xb = (unsigned short*)ws;                       // 134217728 B
  unsigned short* Wb = (unsigned short*)(ws + 134217728L);        // 33554432 B
  unsigned short* RA = (unsigned short*)(ws + 167772160L);        // 1310720 B
  unsigned short* BT = (unsigned short*)(ws + 169082880L);        // 1048576 B
  unsigned short* G  = (unsigned short*)(ws + 180617216L);        // 4194304 B

  hipLaunchKernelGGL(k_cvt, dim3(2048), dim3(256), 0, stream, W_base, Wb, (long)DN * DK / 4);
  hipLaunchKernelGGL(k_build_ra, dim3((RAC * DK + 255) / 256), dim3(256), 0, stream,
                     W_router, lora_A, RA);
  hipLaunchKernelGGL(k_build_bt, dim3((DN * ERC + 255) / 256), dim3(256), 0, stream, lora_B, BT);
  // fused: x->bf16 (writes Xb) + router logits/h GEMM + sparsemax + G
  hipLaunchKernelGGL(k_small_fused, dim3(M_TOK / 64), dim3(256), 0, stream,
                     x, RA, Xb, b_router, G);
  // main fused GEMM (2-phase, 32x32x16 MFMA)
  hipLaunchKernelGGL(k_gemm_main, dim3((M_TOK / 256) * (DN / 256)), dim3(512), 0, stream,
                     Xb, Wb, G, BT, b_base, out);
}

// Round 15
// 627.273 us; speedup vs baseline: 1.1054x; 1.1054x over previous
//
#include <hip/hip_runtime.h>
#include <hip/hip_bf16.h>

// Problem constants (fixed by reference setup_inputs)
#define M_TOK 16384   // B*S = 8*2048
#define DK    4096    // D_IN
#define DN    4096    // D_OUT
#define NE    8       // experts
#define NR    16      // lora rank
#define ERC   128     // E*R
#define RAC   160     // padded router+A columns (8 + 128 + 24 pad)
#define NT64  66      // K-tiles of 64: 64 base + 2 expert

typedef __attribute__((ext_vector_type(8))) short bfrag;   // 8 bf16 (4 VGPRs)
typedef __attribute__((ext_vector_type(4))) float f32x4;   // MFMA acc

__device__ __forceinline__ unsigned short f2bf(float f) {
  unsigned u = __builtin_bit_cast(unsigned, f);
  unsigned rounding = 0x7FFFu + ((u >> 16) & 1u);
  u += rounding;
  return (unsigned short)(u >> 16);
}

__device__ __forceinline__ void load_lds16(const void* g, void* l) {
  __builtin_amdgcn_global_load_lds(
      (__attribute__((address_space(1))) void*)(g),
      (__attribute__((address_space(3))) void*)(l), 16, 0, 0);
}

// ---------- merged prep kernel: W->bf16 | RA build | BT build ----------------
// Block-partitioned single launch (saves 2 kernel-launch overheads):
//   blocks [0, 2048):        W_base f32 -> Wb bf16, grid-stride over float4
//   blocks [2048, 4608):     RA[c][k]: c<8 W_router; 8<=c<136 lora_A; pad 0
//   blocks [4608, 6656):     BT[n][kp] = lora_B[kp][n] transpose -> bf16
#define PREP_W_BLOCKS  2048
#define PREP_RA_BLOCKS 2560   // RAC*DK/256
#define PREP_BT_BLOCKS 2048   // DN*ERC/256
__global__ void k_prep(const float* __restrict__ W_base, unsigned short* __restrict__ Wb,
                       const float* __restrict__ Wr, const float* __restrict__ lA,
                       unsigned short* __restrict__ RA,
                       const float* __restrict__ lB, unsigned short* __restrict__ BT) {
  int b = blockIdx.x;
  if (b < PREP_W_BLOCKS) {
    long n4 = (long)DN * DK / 4;
    long i = (long)b * 256 + threadIdx.x;
    long stride = (long)PREP_W_BLOCKS * 256;
    for (; i < n4; i += stride) {
      float4 v = reinterpret_cast<const float4*>(W_base)[i];
      ushort4 o;
      o.x = f2bf(v.x); o.y = f2bf(v.y); o.z = f2bf(v.z); o.w = f2bf(v.w);
      reinterpret_cast<ushort4*>(Wb)[i] = o;
    }
  } else if (b < PREP_W_BLOCKS + PREP_RA_BLOCKS) {
    int idx = (b - PREP_W_BLOCKS) * 256 + threadIdx.x;
    if (idx >= RAC * DK) return;
    int c = idx >> 12;          // /4096
    int k = idx & (DK - 1);
    float v = 0.f;
    if (c < NE) {
      v = Wr[c * DK + k];
    } else if (c < NE + ERC) {
      int er = c - NE;
      int e = er >> 4, r = er & 15;
      v = lA[((long)e * DK + k) * NR + r];
    }
    RA[idx] = f2bf(v);
  } else {
    int idx = (b - PREP_W_BLOCKS - PREP_RA_BLOCKS) * 256 + threadIdx.x;
    if (idx >= DN * ERC) return;
    int n = idx >> 7;
    int kp = idx & 127;
    BT[idx] = f2bf(lB[(long)kp * DN + n]);
  }
}

// ---------- fused small kernel (R9 proven) -----------------------------------
// Per 64-token block: x f32 -> bf16 (write Xb + stage LDS); GEMM vs RA -> H in
// LDS; sparsemax; write G = w_e * h as bf16.
__global__ __launch_bounds__(256, 2)
void k_small_fused(const float* __restrict__ x, const unsigned short* __restrict__ RA,
                   unsigned short* __restrict__ Xb, const float* __restrict__ b_router,
                   unsigned short* __restrict__ Gout) {
  __shared__ unsigned short At[64 * 64];
  __shared__ unsigned short Bt[RAC * 64];
  __shared__ float Hl[64][160];
  __shared__ float Wl[64][NE];
  int m0 = blockIdx.x * 64;
  int tid = threadIdx.x;
  int lane = tid & 63, wid = tid >> 6;
  int wr = wid >> 1, wc = wid & 1;      // 2x2 waves; wave tile 32 x 80
  int l16 = lane & 15, lhi = lane >> 4;
  f32x4 acc[2][5] = {};
  int row = tid >> 2, c16 = (tid & 3) * 16;
  int byteoff = tid * 16;
  for (int k0 = 0; k0 < DK; k0 += 64) {
    const float* xs = x + (long)(m0 + row) * DK + k0 + c16;
    float4 v0 = *(const float4*)(xs);
    float4 v1 = *(const float4*)(xs + 4);
    float4 v2 = *(const float4*)(xs + 8);
    float4 v3 = *(const float4*)(xs + 12);
    bfrag lo, hi;
    lo[0] = (short)f2bf(v0.x); lo[1] = (short)f2bf(v0.y);
    lo[2] = (short)f2bf(v0.z); lo[3] = (short)f2bf(v0.w);
    lo[4] = (short)f2bf(v1.x); lo[5] = (short)f2bf(v1.y);
    lo[6] = (short)f2bf(v1.z); lo[7] = (short)f2bf(v1.w);
    hi[0] = (short)f2bf(v2.x); hi[1] = (short)f2bf(v2.y);
    hi[2] = (short)f2bf(v2.z); hi[3] = (short)f2bf(v2.w);
    hi[4] = (short)f2bf(v3.x); hi[5] = (short)f2bf(v3.y);
    hi[6] = (short)f2bf(v3.z); hi[7] = (short)f2bf(v3.w);
    unsigned short* xb = Xb + (long)(m0 + row) * DK + k0 + c16;
    *(bfrag*)xb = lo;
    *(bfrag*)(xb + 8) = hi;
    *(bfrag*)&At[row * 64 + c16] = lo;
    *(bfrag*)&At[row * 64 + c16 + 8] = hi;
#pragma unroll
    for (int r = 0; r < 5; r++) {
      int off = r * 4096 + byteoff;
      int rrow = off >> 7, colb = off & 127;
      load_lds16((const char*)RA + ((long)rrow * DK + k0) * 2 + colb, (char*)Bt + off);
    }
    __syncthreads();
#pragma unroll
    for (int kk = 0; kk < 2; kk++) {
      bfrag a[2], b[5];
#pragma unroll
      for (int m = 0; m < 2; m++)
        a[m] = *(const bfrag*)&At[(wr * 32 + m * 16 + l16) * 64 + kk * 32 + lhi * 8];
#pragma unroll
      for (int n = 0; n < 5; n++)
        b[n] = *(const bfrag*)&Bt[(wc * 80 + n * 16 + l16) * 64 + kk * 32 + lhi * 8];
#pragma unroll
      for (int m = 0; m < 2; m++)
#pragma unroll
        for (int n = 0; n < 5; n++)
          acc[m][n] = __builtin_amdgcn_mfma_f32_16x16x32_bf16(a[m], b[n], acc[m][n], 0, 0, 0);
    }
    __syncthreads();
  }
#pragma unroll
  for (int m = 0; m < 2; m++)
#pragma unroll
    for (int n = 0; n < 5; n++) {
      int col = wc * 80 + n * 16 + l16;
      int trow = wr * 32 + m * 16 + lhi * 4;
#pragma unroll
      for (int j = 0; j < 4; j++)
        Hl[trow + j][col] = acc[m][n][j];
    }
  __syncthreads();
  if (tid < 64) {
    float z[NE], zs[NE];
#pragma unroll
    for (int e = 0; e < NE; e++) { z[e] = Hl[tid][e] + b_router[e]; zs[e] = z[e]; }
#pragma unroll
    for (int i = 1; i < NE; i++) {
      float key = zs[i];
      int j = i - 1;
      while (j >= 0 && zs[j] < key) { zs[j + 1] = zs[j]; j--; }
      zs[j + 1] = key;
    }
    float cums[NE];
    float cum = 0.f;
#pragma unroll
    for (int j = 0; j < NE; j++) { cum += zs[j]; cums[j] = cum; }
    int kz = 0;
#pragma unroll
    for (int j = 0; j < NE; j++)
      if (1.f + (float)(j + 1) * zs[j] > cums[j]) kz = j + 1;
    float tau = (cums[kz - 1] - 1.f) / (float)kz;
#pragma unroll
    for (int e = 0; e < NE; e++)
      Wl[tid][e] = fmaxf(z[e] - tau, 0.f);
  }
  __syncthreads();
  for (int idx = tid; idx < 64 * ERC; idx += 256) {
    int tk = idx >> 7, er = idx & 127;
    Gout[(long)(m0 + tk) * ERC + er] = f2bf(Wl[tk][er >> 4] * Hl[tk][NE + er]);
  }
}

// ---------- main GEMM: 8-phase 256x256, BK=64, fused expert (R10 proven) -----
// out = Xb @ Wb^T + bias + G @ BT^T as 66 K-tiles of 64 (64 base + 2 expert).
// LDS 128 KiB: A,B each [2 dbuf][2 TILE-half (rows 0-127 / 128-255)][128][64].
// 8 waves 2Mx4N; wave wr reads A tile-half wr (al rows 0-63 in ph0, ah rows
// 64-127 in ph2); wave wc reads B tile-half wc>>1 in ph0 (bl) + ph1 (bh).
// Stage schedule (each region staged only AFTER its last read phase has
// passed a barrier; t+1 stages go to the opposite dbuf, always safe):
//   ph0: A-h1(t+1) | ph1: none | ph2: B-h0(t+2) | ph3: B-h1(t+2), A-h0(t+2)
// Boundary vmcnt(6)+barrier once per K-tile: per-tile issue order is
// [A-h1(t+1) x2][B-h0(t+2) x2][B-h1(t+2) x2][A-h0(t+2) x2]; keeping the newest
// 6 in flight drains A-h1(t+1) and all older -> tile t+1 fully certified.
// Bank swizzle (rule #21 both-sides, measured 0 conflicts): stored granule =
// logical ^ (row&7); read phys = (kk*4+lhi) ^ (l16&7); source col slot =
// (tid&7) ^ ((tid>>3)&7).
// Measured (R10): 528 us, MfmaUtil 47.3%, SQ_LDS_BANK_CONFLICT = 0.
// NOTE: six schedule variants (barrier count 8/4/2 per tile, drain style,
// barrier placement, 3-slot ring, 32x32 MFMA shape) all measured 46-49%
// MfmaUtil / 527-590 us -- this structure is the best of the explored space.
struct KtArgs {
  const unsigned short *pX, *pW, *pG, *pT;
  int aB, bB, sw0, sw1, tid8;
};

__device__ __forceinline__ void stage_half(unsigned short* lds, const KtArgs& A,
                                           int u, int arr, int h) {
  unsigned short* dst = lds + arr * 32768 + (u & 1) * 16384 + h * 8192 + A.tid8;
  if (u < 64) {
    const unsigned short* s = (arr ? A.pW : A.pX) + (long)(h * 128) * DK + (long)u * 64;
    load_lds16(s, dst);
    load_lds16(s + (long)64 * DK, dst + 4096);
  } else {
    const unsigned short* s = (arr ? A.pT : A.pG) + (long)(h * 128) * ERC + (long)(u - 64) * 64;
    load_lds16(s, dst);
    load_lds16(s + (long)64 * ERC, dst + 4096);
  }
}

template<bool AHI, bool T2, int VMB>
__device__ __forceinline__ void ktile(int t, unsigned short* lds, const KtArgs& A,
                                      f32x4 (&acc)[8][4]) {
  unsigned short* L = lds + (t & 1) * 16384;
  bfrag bl[4], bh[4], al[8], ah[8];
  // ---- ph0: read b_lo(4) + a_lo(8); stage A-h1(t+1) [opposite dbuf] ----
#pragma unroll
  for (int nf = 0; nf < 2; nf++)
#pragma unroll
    for (int kk = 0; kk < 2; kk++)
      bl[nf * 2 + kk] = *(const bfrag*)&L[A.bB + nf * 1024 + (kk ? A.sw1 : A.sw0)];
#pragma unroll
  for (int f = 0; f < 4; f++)
#pragma unroll
    for (int kk = 0; kk < 2; kk++)
      al[f * 2 + kk] = *(const bfrag*)&L[A.aB + f * 1024 + (kk ? A.sw1 : A.sw0)];
  if constexpr (AHI) stage_half(lds, A, t + 1, 0, 1);
  asm volatile("s_waitcnt lgkmcnt(8)" ::: "memory");
  __builtin_amdgcn_s_barrier();
  asm volatile("s_waitcnt lgkmcnt(0)" ::: "memory");
  __builtin_amdgcn_sched_barrier(0);
  __builtin_amdgcn_s_setprio(1);
#pragma unroll
  for (int f = 0; f < 4; f++)
#pragma unroll
    for (int nf = 0; nf < 2; nf++)
#pragma unroll
      for (int kk = 0; kk < 2; kk++)
        acc[f][nf] = __builtin_amdgcn_mfma_f32_16x16x32_bf16(al[f * 2 + kk], bl[nf * 2 + kk], acc[f][nf], 0, 0, 0);
  __builtin_amdgcn_s_setprio(0);
  __builtin_amdgcn_s_barrier();
  // ---- ph1: read b_hi(4); NO stage; Q(lo,hi) ----
#pragma unroll
  for (int nf = 0; nf < 2; nf++)
#pragma unroll
    for (int kk = 0; kk < 2; kk++)
      bh[nf * 2 + kk] = *(const bfrag*)&L[A.bB + (2 + nf) * 1024 + (kk ? A.sw1 : A.sw0)];
  __builtin_amdgcn_s_barrier();
  asm volatile("s_waitcnt lgkmcnt(0)" ::: "memory");
  __builtin_amdgcn_sched_barrier(0);
  __builtin_amdgcn_s_setprio(1);
#pragma unroll
  for (int f = 0; f < 4; f++)
#pragma unroll
    for (int nf = 0; nf < 2; nf++)
#pragma unroll
      for (int kk = 0; kk < 2; kk++)
        acc[f][2 + nf] = __builtin_amdgcn_mfma_f32_16x16x32_bf16(al[f * 2 + kk], bh[nf * 2 + kk], acc[f][2 + nf], 0, 0, 0);
  __builtin_amdgcn_s_setprio(0);
  __builtin_amdgcn_s_barrier();
  // ---- ph2: read a_hi(8); stage B-h0(t+2) [last read was ph1]; Q(hi,lo) ----
#pragma unroll
  for (int f = 0; f < 4; f++)
#pragma unroll
    for (int kk = 0; kk < 2; kk++)
      ah[f * 2 + kk] = *(const bfrag*)&L[A.aB + (4 + f) * 1024 + (kk ? A.sw1 : A.sw0)];
  if constexpr (T2) stage_half(lds, A, t + 2, 1, 0);
  __builtin_amdgcn_s_barrier();
  asm volatile("s_waitcnt lgkmcnt(0)" ::: "memory");
  __builtin_amdgcn_sched_barrier(0);
  __builtin_amdgcn_s_setprio(1);
#pragma unroll
  for (int f = 0; f < 4; f++)
#pragma unroll
    for (int nf = 0; nf < 2; nf++)
#pragma unroll
      for (int kk = 0; kk < 2; kk++)
        acc[4 + f][nf] = __builtin_amdgcn_mfma_f32_16x16x32_bf16(ah[f * 2 + kk], bl[nf * 2 + kk], acc[4 + f][nf], 0, 0, 0);
  __builtin_amdgcn_s_setprio(0);
  __builtin_amdgcn_s_barrier();
  // ---- ph3: no reads; stage B-h1(t+2) + A-h0(t+2) [last reads ph1/ph2]; Q(hi,hi) ----
  if constexpr (T2) {
    stage_half(lds, A, t + 2, 1, 1);
    stage_half(lds, A, t + 2, 0, 0);
  }
  __builtin_amdgcn_s_setprio(1);
#pragma unroll
  for (int f = 0; f < 4; f++)
#pragma unroll
    for (int nf = 0; nf < 2; nf++)
#pragma unroll
      for (int kk = 0; kk < 2; kk++)
        acc[4 + f][2 + nf] = __builtin_amdgcn_mfma_f32_16x16x32_bf16(ah[f * 2 + kk], bh[nf * 2 + kk], acc[4 + f][2 + nf], 0, 0, 0);
  __builtin_amdgcn_s_setprio(0);
  if constexpr (VMB == 6)      asm volatile("s_waitcnt vmcnt(6)\n\ts_barrier" ::: "memory");
  else if constexpr (VMB == 0) asm volatile("s_waitcnt vmcnt(0)\n\ts_barrier" ::: "memory");
  // VMB < 0: last tile, no boundary
}

__global__ __launch_bounds__(512, 2)
void k_gemm_main(const unsigned short* __restrict__ X, const unsigned short* __restrict__ W,
                 const unsigned short* __restrict__ G, const unsigned short* __restrict__ BT,
                 const float* __restrict__ bias, float* __restrict__ out) {
  // A: [2 dbuf][2 half][128][64] at 0; B: same at 32768 (shorts). 128 KiB total.
  __shared__ unsigned short lds[65536];
  int bid = blockIdx.x;
  // XCD-aware swizzle: 1024 workgroups, 8 XCDs -> contiguous chunks of 128
  int swz = (bid & 7) * 128 + (bid >> 3);
  int bm = swz >> 4, bn = swz & 15;
  int m0 = bm * 256, n0 = bn * 256;
  int tid = threadIdx.x;
  int lane = tid & 63, wid = tid >> 6;
  int wr = wid >> 2, wc = wid & 3;      // 2x4 waves; wave tile 128 x 64
  int l16 = lane & 15, lhi = lane >> 4;

  KtArgs A;
  A.sw0 = (lhi ^ (l16 & 7)) * 8;
  A.sw1 = ((4 + lhi) ^ (l16 & 7)) * 8;
  A.aB = wr * 8192 + l16 * 64;
  A.bB = 32768 + (wc >> 1) * 8192 + ((wc & 1) * 64 + l16) * 64;
  A.tid8 = tid * 8;
  int swz8 = ((tid & 7) ^ ((tid >> 3) & 7)) * 8;    // pre-swizzled source slot
  int r0 = tid >> 3;
  A.pX = X + (long)(m0 + r0) * DK + swz8;
  A.pW = W + (long)(n0 + r0) * DK + swz8;
  A.pG = G + (long)(m0 + r0) * ERC + swz8;
  A.pT = BT + (long)(n0 + r0) * ERC + swz8;

  f32x4 acc[8][4] = {};

  // prologue: tile0 all 4 halves, then tile1 {A-h0, B-h0, B-h1} (A-h1(1) comes
  // from tile 0's ph0). vmcnt(6) -> tile 0's 8 oldest loads drained.
  stage_half(lds, A, 0, 0, 0);
  stage_half(lds, A, 0, 1, 0);
  stage_half(lds, A, 0, 1, 1);
  stage_half(lds, A, 0, 0, 1);
  stage_half(lds, A, 1, 0, 0);
  stage_half(lds, A, 1, 1, 0);
  stage_half(lds, A, 1, 1, 1);
  asm volatile("s_waitcnt vmcnt(6)\n\ts_barrier" ::: "memory");

  for (int t = 0; t < 64; t++)
    ktile<true, true, 6>(t, lds, A, acc);
  ktile<true, false, 0>(64, lds, A, acc);
  ktile<false, false, -1>(65, lds, A, acc);

  // epilogue: bias + f32 store
#pragma unroll
  for (int nf = 0; nf < 4; nf++) {
    int col = n0 + wc * 64 + nf * 16 + l16;
    float bv = bias[col];
#pragma unroll
    for (int f = 0; f < 8; f++) {
      int row = m0 + wr * 128 + f * 16 + lhi * 4;
#pragma unroll
      for (int j = 0; j < 4; j++)
        out[(long)(row + j) * DN + col] = acc[f][nf][j] + bv;
    }
  }
}

extern "C" void kernel_launch(void* const* d_in, const int* in_sizes, int n_in,
                              void* d_out, int out_size, void* d_ws, size_t ws_size,
                              hipStream_t stream) {
  const float* x        = (const float*)d_in[0];
  const float* W_base   = (const float*)d_in[1];
  const float* b_base   = (const float*)d_in[2];
  const float* W_router = (const float*)d_in[3];
  const float* b_router = (const float*)d_in[4];
  const float* lora_A   = (const float*)d_in[5];
  const float* lora_B   = (const float*)d_in[6];
  float* out = (float*)d_out;

  char* ws = (char*)d_ws;
  unsigned short* Xb = (unsigned short*)ws;                       // 134217728 B
  unsigned short* Wb = (unsigned short*)(ws + 134217728L);        // 33554432 B
  unsigned short* RA = (unsigned short*)(ws + 167772160L);        // 1310720 B
  unsigned short* BT = (unsigned short*)(ws + 169082880L);        // 1048576 B
  unsigned short* G  = (unsigned short*)(ws + 180617216L);        // 4194304 B

  // merged prep: W->bf16 | RA build | BT build (one launch)
  hipLaunchKernelGGL(k_prep, dim3(PREP_W_BLOCKS + PREP_RA_BLOCKS + PREP_BT_BLOCKS),
                     dim3(256), 0, stream, W_base, Wb, W_router, lora_A, RA, lora_B, BT);
  // fused: x->bf16 (writes Xb) + router logits/h GEMM + sparsemax + G
  hipLaunchKernelGGL(k_small_fused, dim3(M_TOK / 64), dim3(256), 0, stream,
                     x, RA, Xb, b_router, G);
  // main fused GEMM (8-phase, R10 proven best)
  hipLaunchKernelGGL(k_gemm_main, dim3((M_TOK / 256) * (DN / 256)), dim3(512), 0, stream,
                     Xb, Wb, G, BT, b_base, out);
}

// Round 16
// 626.874 us; speedup vs baseline: 1.1061x; 1.0006x over previous
//
#include <hip/hip_runtime.h>
#include <hip/hip_bf16.h>

// Problem constants (fixed by reference setup_inputs)
#define M_TOK 16384   // B*S = 8*2048
#define DK    4096    // D_IN
#define DN    4096    // D_OUT
#define NE    8       // experts
#define NR    16      // lora rank
#define ERC   128     // E*R
#define RAC   160     // padded router+A columns (8 + 128 + 24 pad)
#define NT64  66      // K-tiles of 64: 64 base + 2 expert

typedef __attribute__((ext_vector_type(8))) short bfrag;   // 8 bf16 (4 VGPRs)
typedef __attribute__((ext_vector_type(4))) float f32x4;   // MFMA acc

__device__ __forceinline__ unsigned short f2bf(float f) {
  unsigned u = __builtin_bit_cast(unsigned, f);
  unsigned rounding = 0x7FFFu + ((u >> 16) & 1u);
  u += rounding;
  return (unsigned short)(u >> 16);
}

__device__ __forceinline__ void load_lds16(const void* g, void* l) {
  __builtin_amdgcn_global_load_lds(
      (__attribute__((address_space(1))) void*)(g),
      (__attribute__((address_space(3))) void*)(l), 16, 0, 0);
}

// ---------- merged prep kernel: W->bf16 | RA build | BT build ----------------
#define PREP_W_BLOCKS  2048
#define PREP_RA_BLOCKS 2560   // RAC*DK/256
#define PREP_BT_BLOCKS 2048   // DN*ERC/256
__global__ void k_prep(const float* __restrict__ W_base, unsigned short* __restrict__ Wb,
                       const float* __restrict__ Wr, const float* __restrict__ lA,
                       unsigned short* __restrict__ RA,
                       const float* __restrict__ lB, unsigned short* __restrict__ BT) {
  int b = blockIdx.x;
  if (b < PREP_W_BLOCKS) {
    long n4 = (long)DN * DK / 4;
    long i = (long)b * 256 + threadIdx.x;
    long stride = (long)PREP_W_BLOCKS * 256;
    for (; i < n4; i += stride) {
      float4 v = reinterpret_cast<const float4*>(W_base)[i];
      ushort4 o;
      o.x = f2bf(v.x); o.y = f2bf(v.y); o.z = f2bf(v.z); o.w = f2bf(v.w);
      reinterpret_cast<ushort4*>(Wb)[i] = o;
    }
  } else if (b < PREP_W_BLOCKS + PREP_RA_BLOCKS) {
    int idx = (b - PREP_W_BLOCKS) * 256 + threadIdx.x;
    if (idx >= RAC * DK) return;
    int c = idx >> 12;          // /4096
    int k = idx & (DK - 1);
    float v = 0.f;
    if (c < NE) {
      v = Wr[c * DK + k];
    } else if (c < NE + ERC) {
      int er = c - NE;
      int e = er >> 4, r = er & 15;
      v = lA[((long)e * DK + k) * NR + r];
    }
    RA[idx] = f2bf(v);
  } else {
    int idx = (b - PREP_W_BLOCKS - PREP_RA_BLOCKS) * 256 + threadIdx.x;
    if (idx >= DN * ERC) return;
    int n = idx >> 7;
    int kp = idx & 127;
    BT[idx] = f2bf(lB[(long)kp * DN + n]);
  }
}

// ---------- fused small kernel (R9 proven) -----------------------------------
// Per 64-token block: x f32 -> bf16 (write Xb + stage LDS); GEMM vs RA -> H in
// LDS; sparsemax; write G = w_e * h as bf16.
__global__ __launch_bounds__(256, 2)
void k_small_fused(const float* __restrict__ x, const unsigned short* __restrict__ RA,
                   unsigned short* __restrict__ Xb, const float* __restrict__ b_router,
                   unsigned short* __restrict__ Gout) {
  __shared__ unsigned short At[64 * 64];
  __shared__ unsigned short Bt[RAC * 64];
  __shared__ float Hl[64][160];
  __shared__ float Wl[64][NE];
  int m0 = blockIdx.x * 64;
  int tid = threadIdx.x;
  int lane = tid & 63, wid = tid >> 6;
  int wr = wid >> 1, wc = wid & 1;      // 2x2 waves; wave tile 32 x 80
  int l16 = lane & 15, lhi = lane >> 4;
  f32x4 acc[2][5] = {};
  int row = tid >> 2, c16 = (tid & 3) * 16;
  int byteoff = tid * 16;
  for (int k0 = 0; k0 < DK; k0 += 64) {
    const float* xs = x + (long)(m0 + row) * DK + k0 + c16;
    float4 v0 = *(const float4*)(xs);
    float4 v1 = *(const float4*)(xs + 4);
    float4 v2 = *(const float4*)(xs + 8);
    float4 v3 = *(const float4*)(xs + 12);
    bfrag lo, hi;
    lo[0] = (short)f2bf(v0.x); lo[1] = (short)f2bf(v0.y);
    lo[2] = (short)f2bf(v0.z); lo[3] = (short)f2bf(v0.w);
    lo[4] = (short)f2bf(v1.x); lo[5] = (short)f2bf(v1.y);
    lo[6] = (short)f2bf(v1.z); lo[7] = (short)f2bf(v1.w);
    hi[0] = (short)f2bf(v2.x); hi[1] = (short)f2bf(v2.y);
    hi[2] = (short)f2bf(v2.z); hi[3] = (short)f2bf(v2.w);
    hi[4] = (short)f2bf(v3.x); hi[5] = (short)f2bf(v3.y);
    hi[6] = (short)f2bf(v3.z); hi[7] = (short)f2bf(v3.w);
    unsigned short* xb = Xb + (long)(m0 + row) * DK + k0 + c16;
    *(bfrag*)xb = lo;
    *(bfrag*)(xb + 8) = hi;
    *(bfrag*)&At[row * 64 + c16] = lo;
    *(bfrag*)&At[row * 64 + c16 + 8] = hi;
#pragma unroll
    for (int r = 0; r < 5; r++) {
      int off = r * 4096 + byteoff;
      int rrow = off >> 7, colb = off & 127;
      load_lds16((const char*)RA + ((long)rrow * DK + k0) * 2 + colb, (char*)Bt + off);
    }
    __syncthreads();
#pragma unroll
    for (int kk = 0; kk < 2; kk++) {
      bfrag a[2], b[5];
#pragma unroll
      for (int m = 0; m < 2; m++)
        a[m] = *(const bfrag*)&At[(wr * 32 + m * 16 + l16) * 64 + kk * 32 + lhi * 8];
#pragma unroll
      for (int n = 0; n < 5; n++)
        b[n] = *(const bfrag*)&Bt[(wc * 80 + n * 16 + l16) * 64 + kk * 32 + lhi * 8];
#pragma unroll
      for (int m = 0; m < 2; m++)
#pragma unroll
        for (int n = 0; n < 5; n++)
          acc[m][n] = __builtin_amdgcn_mfma_f32_16x16x32_bf16(a[m], b[n], acc[m][n], 0, 0, 0);
    }
    __syncthreads();
  }
#pragma unroll
  for (int m = 0; m < 2; m++)
#pragma unroll
    for (int n = 0; n < 5; n++) {
      int col = wc * 80 + n * 16 + l16;
      int trow = wr * 32 + m * 16 + lhi * 4;
#pragma unroll
      for (int j = 0; j < 4; j++)
        Hl[trow + j][col] = acc[m][n][j];
    }
  __syncthreads();
  if (tid < 64) {
    float z[NE], zs[NE];
#pragma unroll
    for (int e = 0; e < NE; e++) { z[e] = Hl[tid][e] + b_router[e]; zs[e] = z[e]; }
#pragma unroll
    for (int i = 1; i < NE; i++) {
      float key = zs[i];
      int j = i - 1;
      while (j >= 0 && zs[j] < key) { zs[j + 1] = zs[j]; j--; }
      zs[j + 1] = key;
    }
    float cums[NE];
    float cum = 0.f;
#pragma unroll
    for (int j = 0; j < NE; j++) { cum += zs[j]; cums[j] = cum; }
    int kz = 0;
#pragma unroll
    for (int j = 0; j < NE; j++)
      if (1.f + (float)(j + 1) * zs[j] > cums[j]) kz = j + 1;
    float tau = (cums[kz - 1] - 1.f) / (float)kz;
#pragma unroll
    for (int e = 0; e < NE; e++)
      Wl[tid][e] = fmaxf(z[e] - tau, 0.f);
  }
  __syncthreads();
  for (int idx = tid; idx < 64 * ERC; idx += 256) {
    int tk = idx >> 7, er = idx & 127;
    Gout[(long)(m0 + tk) * ERC + er] = f2bf(Wl[tk][er >> 4] * Hl[tk][NE + er]);
  }
}

// ---------- main GEMM: 8-phase 256x256, BK=64, fused expert (best measured) --
// out = Xb @ Wb^T + bias + G @ BT^T as 66 K-tiles of 64 (64 base + 2 expert).
// Measured: 527-540 us, MfmaUtil 47.5%, SQ_LDS_BANK_CONFLICT = 0, 1042 TF eff.
// STRUCTURAL CEILING NOTE (rounds 5-14): per CU per K-tile, matrix pipe needs
// ~2484 cyc and the LDS pipe ~2300 cyc; measured 4790 = their SUM. MFMA blocks
// its wave (no async MFMA on CDNA4), workgroup barriers phase-lock all 8
// waves, and the 512-reg/SIMD pool pins this 248-reg/wave tile at 1 block/CU
// -- so no intra-wave, inter-wave, or inter-block overlap source exists in
// this design family. 7 variants (barrier count 8/4/2/1 per tile, drain
// style, barrier placement, 3-slot ring, 32x32 shape, 2-block) all measured
// 46-49% MfmaUtil. Breaking the sum requires producer/consumer wave
// specialization without workgroup barriers (AITER/HK-class machinery).
struct KtArgs {
  const unsigned short *pX, *pW, *pG, *pT;
  int aB, bB, sw0, sw1, tid8;
};

__device__ __forceinline__ void stage_half(unsigned short* lds, const KtArgs& A,
                                           int u, int arr, int h) {
  unsigned short* dst = lds + arr * 32768 + (u & 1) * 16384 + h * 8192 + A.tid8;
  if (u < 64) {
    const unsigned short* s = (arr ? A.pW : A.pX) + (long)(h * 128) * DK + (long)u * 64;
    load_lds16(s, dst);
    load_lds16(s + (long)64 * DK, dst + 4096);
  } else {
    const unsigned short* s = (arr ? A.pT : A.pG) + (long)(h * 128) * ERC + (long)(u - 64) * 64;
    load_lds16(s, dst);
    load_lds16(s + (long)64 * ERC, dst + 4096);
  }
}

template<bool AHI, bool T2, int VMB>
__device__ __forceinline__ void ktile(int t, unsigned short* lds, const KtArgs& A,
                                      f32x4 (&acc)[8][4]) {
  unsigned short* L = lds + (t & 1) * 16384;
  bfrag bl[4], bh[4], al[8], ah[8];
  // ---- ph0: read b_lo(4) + a_lo(8); stage A-h1(t+1) [opposite dbuf] ----
#pragma unroll
  for (int nf = 0; nf < 2; nf++)
#pragma unroll
    for (int kk = 0; kk < 2; kk++)
      bl[nf * 2 + kk] = *(const bfrag*)&L[A.bB + nf * 1024 + (kk ? A.sw1 : A.sw0)];
#pragma unroll
  for (int f = 0; f < 4; f++)
#pragma unroll
    for (int kk = 0; kk < 2; kk++)
      al[f * 2 + kk] = *(const bfrag*)&L[A.aB + f * 1024 + (kk ? A.sw1 : A.sw0)];
  if constexpr (AHI) stage_half(lds, A, t + 1, 0, 1);
  asm volatile("s_waitcnt lgkmcnt(8)" ::: "memory");
  __builtin_amdgcn_s_barrier();
  asm volatile("s_waitcnt lgkmcnt(0)" ::: "memory");
  __builtin_amdgcn_sched_barrier(0);
  __builtin_amdgcn_s_setprio(1);
#pragma unroll
  for (int f = 0; f < 4; f++)
#pragma unroll
    for (int nf = 0; nf < 2; nf++)
#pragma unroll
      for (int kk = 0; kk < 2; kk++)
        acc[f][nf] = __builtin_amdgcn_mfma_f32_16x16x32_bf16(al[f * 2 + kk], bl[nf * 2 + kk], acc[f][nf], 0, 0, 0);
  __builtin_amdgcn_s_setprio(0);
  __builtin_amdgcn_s_barrier();
  // ---- ph1: read b_hi(4); NO stage; Q(lo,hi) ----
#pragma unroll
  for (int nf = 0; nf < 2; nf++)
#pragma unroll
    for (int kk = 0; kk < 2; kk++)
      bh[nf * 2 + kk] = *(const bfrag*)&L[A.bB + (2 + nf) * 1024 + (kk ? A.sw1 : A.sw0)];
  __builtin_amdgcn_s_barrier();
  asm volatile("s_waitcnt lgkmcnt(0)" ::: "memory");
  __builtin_amdgcn_sched_barrier(0);
  __builtin_amdgcn_s_setprio(1);
#pragma unroll
  for (int f = 0; f < 4; f++)
#pragma unroll
    for (int nf = 0; nf < 2; nf++)
#pragma unroll
      for (int kk = 0; kk < 2; kk++)
        acc[f][2 + nf] = __builtin_amdgcn_mfma_f32_16x16x32_bf16(al[f * 2 + kk], bh[nf * 2 + kk], acc[f][2 + nf], 0, 0, 0);
  __builtin_amdgcn_s_setprio(0);
  __builtin_amdgcn_s_barrier();
  // ---- ph2: read a_hi(8); stage B-h0(t+2) [last read was ph1]; Q(hi,lo) ----
#pragma unroll
  for (int f = 0; f < 4; f++)
#pragma unroll
    for (int kk = 0; kk < 2; kk++)
      ah[f * 2 + kk] = *(const bfrag*)&L[A.aB + (4 + f) * 1024 + (kk ? A.sw1 : A.sw0)];
  if constexpr (T2) stage_half(lds, A, t + 2, 1, 0);
  __builtin_amdgcn_s_barrier();
  asm volatile("s_waitcnt lgkmcnt(0)" ::: "memory");
  __builtin_amdgcn_sched_barrier(0);
  __builtin_amdgcn_s_setprio(1);
#pragma unroll
  for (int f = 0; f < 4; f++)
#pragma unroll
    for (int nf = 0; nf < 2; nf++)
#pragma unroll
      for (int kk = 0; kk < 2; kk++)
        acc[4 + f][nf] = __builtin_amdgcn_mfma_f32_16x16x32_bf16(ah[f * 2 + kk], bl[nf * 2 + kk], acc[4 + f][nf], 0, 0, 0);
  __builtin_amdgcn_s_setprio(0);
  __builtin_amdgcn_s_barrier();
  // ---- ph3: no reads; stage B-h1(t+2) + A-h0(t+2) [last reads ph1/ph2]; Q(hi,hi) ----
  if constexpr (T2) {
    stage_half(lds, A, t + 2, 1, 1);
    stage_half(lds, A, t + 2, 0, 0);
  }
  __builtin_amdgcn_s_setprio(1);
#pragma unroll
  for (int f = 0; f < 4; f++)
#pragma unroll
    for (int nf = 0; nf < 2; nf++)
#pragma unroll
      for (int kk = 0; kk < 2; kk++)
        acc[4 + f][2 + nf] = __builtin_amdgcn_mfma_f32_16x16x32_bf16(ah[f * 2 + kk], bh[nf * 2 + kk], acc[4 + f][2 + nf], 0, 0, 0);
  __builtin_amdgcn_s_setprio(0);
  if constexpr (VMB == 6)      asm volatile("s_waitcnt vmcnt(6)\n\ts_barrier" ::: "memory");
  else if constexpr (VMB == 0) asm volatile("s_waitcnt vmcnt(0)\n\ts_barrier" ::: "memory");
  // VMB < 0: last tile, no boundary
}

__global__ __launch_bounds__(512, 2)
void k_gemm_main(const unsigned short* __restrict__ X, const unsigned short* __restrict__ W,
                 const unsigned short* __restrict__ G, const unsigned short* __restrict__ BT,
                 const float* __restrict__ bias, float* __restrict__ out) {
  // A: [2 dbuf][2 half][128][64] at 0; B: same at 32768 (shorts). 128 KiB total.
  __shared__ unsigned short lds[65536];
  int bid = blockIdx.x;
  // XCD-aware swizzle: 1024 workgroups, 8 XCDs -> contiguous chunks of 128
  int swz = (bid & 7) * 128 + (bid >> 3);
  int bm = swz >> 4, bn = swz & 15;
  int m0 = bm * 256, n0 = bn * 256;
  int tid = threadIdx.x;
  int lane = tid & 63, wid = tid >> 6;
  int wr = wid >> 2, wc = wid & 3;      // 2x4 waves; wave tile 128 x 64
  int l16 = lane & 15, lhi = lane >> 4;

  KtArgs A;
  A.sw0 = (lhi ^ (l16 & 7)) * 8;
  A.sw1 = ((4 + lhi) ^ (l16 & 7)) * 8;
  A.aB = wr * 8192 + l16 * 64;
  A.bB = 32768 + (wc >> 1) * 8192 + ((wc & 1) * 64 + l16) * 64;
  A.tid8 = tid * 8;
  int swz8 = ((tid & 7) ^ ((tid >> 3) & 7)) * 8;    // pre-swizzled source slot
  int r0 = tid >> 3;
  A.pX = X + (long)(m0 + r0) * DK + swz8;
  A.pW = W + (long)(n0 + r0) * DK + swz8;
  A.pG = G + (long)(m0 + r0) * ERC + swz8;
  A.pT = BT + (long)(n0 + r0) * ERC + swz8;

  f32x4 acc[8][4] = {};

  // prologue: tile0 all 4 halves, then tile1 {A-h0, B-h0, B-h1} (A-h1(1) comes
  // from tile 0's ph0). vmcnt(6) -> tile 0's 8 oldest loads drained.
  stage_half(lds, A, 0, 0, 0);
  stage_half(lds, A, 0, 1, 0);
  stage_half(lds, A, 0, 1, 1);
  stage_half(lds, A, 0, 0, 1);
  stage_half(lds, A, 1, 0, 0);
  stage_half(lds, A, 1, 1, 0);
  stage_half(lds, A, 1, 1, 1);
  asm volatile("s_waitcnt vmcnt(6)\n\ts_barrier" ::: "memory");

  for (int t = 0; t < 64; t++)
    ktile<true, true, 6>(t, lds, A, acc);
  ktile<true, false, 0>(64, lds, A, acc);
  ktile<false, false, -1>(65, lds, A, acc);

  // epilogue: bias + f32 store
#pragma unroll
  for (int nf = 0; nf < 4; nf++) {
    int col = n0 + wc * 64 + nf * 16 + l16;
    float bv = bias[col];
#pragma unroll
    for (int f = 0; f < 8; f++) {
      int row = m0 + wr * 128 + f * 16 + lhi * 4;
#pragma unroll
      for (int j = 0; j < 4; j++)
        out[(long)(row + j) * DN + col] = acc[f][nf][j] + bv;
    }
  }
}

extern "C" void kernel_launch(void* const* d_in, const int* in_sizes, int n_in,
                              void* d_out, int out_size, void* d_ws, size_t ws_size,
                              hipStream_t stream) {
  const float* x        = (const float*)d_in[0];
  const float* W_base   = (const float*)d_in[1];
  const float* b_base   = (const float*)d_in[2];
  const float* W_router = (const float*)d_in[3];
  const float* b_router = (const float*)d_in[4];
  const float* lora_A   = (const float*)d_in[5];
  const float* lora_B   = (const float*)d_in[6];
  float* out = (float*)d_out;

  char* ws = (char*)d_ws;
  unsigned short* Xb = (unsigned short*)ws;                       // 134217728 B
  unsigned short* Wb = (unsigned short*)(ws + 134217728L);        // 33554432 B
  unsigned short* RA = (unsigned short*)(ws + 167772160L);        // 1310720 B
  unsigned short* BT = (unsigned short*)(ws + 169082880L);        // 1048576 B
  unsigned short* G  = (unsigned short*)(ws + 180617216L);        // 4194304 B

  // merged prep: W->bf16 | RA build | BT build (one launch)
  hipLaunchKernelGGL(k_prep, dim3(PREP_W_BLOCKS + PREP_RA_BLOCKS + PREP_BT_BLOCKS),
                     dim3(256), 0, stream, W_base, Wb, W_router, lora_A, RA, lora_B, BT);
  // fused: x->bf16 (writes Xb) + router logits/h GEMM + sparsemax + G
  hipLaunchKernelGGL(k_small_fused, dim3(M_TOK / 64), dim3(256), 0, stream,
                     x, RA, Xb, b_router, G);
  // main fused GEMM (8-phase, best measured)
  hipLaunchKernelGGL(k_gemm_main, dim3((M_TOK / 256) * (DN / 256)), dim3(512), 0, stream,
                     Xb, Wb, G, BT, b_base, out);
}